// Round 4
// baseline (1630.533 us; speedup 1.0000x reference)
//
#include <hip/hip_runtime.h>

#define N_NODES 100000
#define N_EDGES 3200000
#define N_GRAPHS 1024
#define NCLS 21
#define TILE_N 128
#define K_BUCKETS 782          // ceil(100000/128)
#define NB 256                 // binning blocks
#define CHUNK 12500            // N_EDGES / NB
#define SCAN_N (K_BUCKETS*NB)  // 200192
#define SCAN_NB1 196           // ceil(SCAN_N/1024)

__device__ __forceinline__ float rlanef(float v, int l) {
    return __int_as_float(__builtin_amdgcn_readlane(__float_as_int(v), l));
}

// ---- pass 1: per-block bucket histogram (no global deg atomics) ----
__global__ __launch_bounds__(256) void k_hist(const int* __restrict__ dst,
                                              int* __restrict__ gh) {
    __shared__ int lh[K_BUCKETS];
    for (int i = threadIdx.x; i < K_BUCKETS; i += 256) lh[i] = 0;
    __syncthreads();
    int e0 = blockIdx.x * CHUNK;
    for (int e = e0 + threadIdx.x; e < e0 + CHUNK; e += 256)
        atomicAdd(&lh[dst[e] >> 7], 1);
    __syncthreads();
    for (int i = threadIdx.x; i < K_BUCKETS; i += 256) gh[i * NB + blockIdx.x] = lh[i];
}

// ---- exclusive scan, IN-PLACE over buf (3 kernels) ----
__global__ void k_scan1(int* __restrict__ buf, int* __restrict__ bsum, int n) {
    __shared__ int lds[256];
    int t = threadIdx.x;
    int base = blockIdx.x * 1024 + t * 4;
    int v[4];
#pragma unroll
    for (int i = 0; i < 4; i++) v[i] = (base + i < n) ? buf[base + i] : 0;
    int tsum = v[0] + v[1] + v[2] + v[3];
    lds[t] = tsum;
    __syncthreads();
    for (int off = 1; off < 256; off <<= 1) {
        int cur = lds[t];
        int add = (t >= off) ? lds[t - off] : 0;
        __syncthreads();
        lds[t] = cur + add;
        __syncthreads();
    }
    int run = lds[t] - tsum;
#pragma unroll
    for (int i = 0; i < 4; i++) {
        if (base + i < n) buf[base + i] = run;
        run += v[i];
    }
    if (t == 255) bsum[blockIdx.x] = lds[255];
}

__global__ void k_scan2(int* __restrict__ bsum, int nb) {
    if (threadIdx.x == 0 && blockIdx.x == 0) {
        int acc = 0;
        for (int b = 0; b < nb; b++) { int t = bsum[b]; bsum[b] = acc; acc += t; }
    }
}

__global__ void k_scan3(int* __restrict__ buf, const int* __restrict__ bsum, int n) {
    int i = blockIdx.x * 256 + threadIdx.x;
    if (i < n) buf[i] += bsum[i >> 10];
}

// ---- pass 2: deterministic bin, block-private runs, no global atomics ----
// payload: (src << 7) | (dst & 127)
__global__ __launch_bounds__(256) void k_bin(const int* __restrict__ src,
                                             const int* __restrict__ dst,
                                             const int* __restrict__ S,
                                             unsigned int* __restrict__ bins) {
    __shared__ int cur[K_BUCKETS];
    for (int i = threadIdx.x; i < K_BUCKETS; i += 256) cur[i] = S[i * NB + blockIdx.x];
    __syncthreads();
    int e0 = blockIdx.x * CHUNK;
    for (int e = e0 + threadIdx.x; e < e0 + CHUNK; e += 256) {
        int dd = dst[e];
        int pos = atomicAdd(&cur[dd >> 7], 1);
        bins[pos] = ((unsigned int)src[e] << 7) | (unsigned int)(dd & 127);
    }
}

// ---- layer 1 fused: bucket aggregate + count + linear + relu -> h1, cnt, gcnt ----
__global__ __launch_bounds__(256) void k_l1agg(
    const int* __restrict__ S, const unsigned int* __restrict__ bins,
    const float* __restrict__ x,
    const float* __restrict__ W1l, const float* __restrict__ b1,
    const float* __restrict__ W1r,
    const int* __restrict__ batch, float* __restrict__ gcnt,
    float* __restrict__ h1, int* __restrict__ cnt) {
    __shared__ float t1[TILE_N];
    __shared__ int   tc[TILE_N];
    int k = blockIdx.x;
    if (threadIdx.x < TILE_N) { t1[threadIdx.x] = 0.0f; tc[threadIdx.x] = 0; }
    __syncthreads();
    int e0 = S[k * NB];
    int e1 = (k == K_BUCKETS - 1) ? N_EDGES : S[(k + 1) * NB];
    for (int i = e0 + threadIdx.x; i < e1; i += 256) {
        unsigned int p = bins[i];
        atomicAdd(&t1[p & 127u], x[p >> 7]);
        atomicAdd(&tc[p & 127u], 1);
    }
    __syncthreads();
    if (threadIdx.x < TILE_N) {
        int n = k * TILE_N + threadIdx.x;
        if (n < N_NODES) {
            cnt[n] = tc[threadIdx.x];
            atomicAdd(&gcnt[batch[n]], 1.0f);
        }
    }
    // node update for the 128 nodes of this tile
    for (int i = threadIdx.x; i < TILE_N * 64; i += 256) {
        int slot = i >> 6, f = i & 63;
        int n = k * TILE_N + slot;
        if (n >= N_NODES) break;
        float a = t1[slot] / fmaxf((float)tc[slot], 1.0f);
        float v = a * W1l[f] + b1[f] + x[n] * W1r[f];
        h1[(size_t)n * 64 + f] = fmaxf(v, 0.0f);
    }
}

// ---- layer 2 fused: bucket tile aggregate + W2 GEMV + relu + mean-pool ----
__global__ __launch_bounds__(256) void k_node2(
    const int* __restrict__ S, const unsigned int* __restrict__ bins,
    const float* __restrict__ h1, const int* __restrict__ cnt,
    const float* __restrict__ W2l, const float* __restrict__ b2,
    const float* __restrict__ W2r,
    const int* __restrict__ batch, const float* __restrict__ gcnt,
    float* __restrict__ pooled) {
    __shared__ float tile[TILE_N * 64];   // 32 KB
    int k = blockIdx.x;
    int f = threadIdx.x & 63;
    int wid = threadIdx.x >> 6;
    for (int i = threadIdx.x; i < TILE_N * 64; i += 256) tile[i] = 0.0f;
    __syncthreads();

    int e0 = S[k * NB];
    int e1 = (k == K_BUCKETS - 1) ? N_EDGES : S[(k + 1) * NB];
    for (int g = e0 + wid * 64; g < e1; g += 256) {
        int idx = g + f;
        unsigned int p = (idx < e1) ? bins[idx] : 0u;
        int d = (int)(p & 127u);
        int s = (int)(p >> 7);
        int c = min(64, e1 - g);
        int j = 0;
        for (; j + 8 <= c; j += 8) {
            int dd[8]; float vv[8];
#pragma unroll
            for (int i = 0; i < 8; i++) {
                dd[i] = __builtin_amdgcn_readlane(d, j + i);
                int sj = __builtin_amdgcn_readlane(s, j + i);
                vv[i] = h1[(size_t)sj * 64 + f];   // coalesced 256B/edge, 8 in flight
            }
#pragma unroll
            for (int i = 0; i < 8; i++) atomicAdd(&tile[dd[i] * 64 + f], vv[i]);
        }
        for (; j < c; ++j) {
            int dj = __builtin_amdgcn_readlane(d, j);
            int sj = __builtin_amdgcn_readlane(s, j);
            atomicAdd(&tile[dj * 64 + f], h1[(size_t)sj * 64 + f]);
        }
    }
    __syncthreads();

    float wl[64], wr[64];
#pragma unroll
    for (int kk = 0; kk < 64; kk++) {
        wl[kk] = W2l[kk * 64 + f];
        wr[kk] = W2r[kk * 64 + f];
    }
    float bias = b2[f];
    for (int t = wid; t < TILE_N; t += 4) {
        int n = k * TILE_N + t;
        if (n >= N_NODES) break;
        float m = tile[t * 64 + f] / fmaxf((float)cnt[n], 1.0f);
        float h = h1[(size_t)n * 64 + f];
        float acc = bias;
#pragma unroll
        for (int kk = 0; kk < 64; kk++) {
            acc += rlanef(m, kk) * wl[kk];
            acc += rlanef(h, kk) * wr[kk];
        }
        acc = fmaxf(acc, 0.0f);
        int b = batch[n];
        atomicAdd(&pooled[b * 64 + f], acc / fmaxf(gcnt[b], 1.0f));
    }
}

// ---- classifier ----
__global__ void k_cls(const float* __restrict__ pooled, const float* __restrict__ Wc,
                      const float* __restrict__ bc, float* __restrict__ out) {
    __shared__ float rowv[64];
    int g = blockIdx.x;
    int f = threadIdx.x;
    rowv[f] = pooled[g * 64 + f];
    __syncthreads();
    if (f < NCLS) {
        float acc = bc[f];
#pragma unroll
        for (int kk = 0; kk < 64; kk++) acc += rowv[kk] * Wc[kk * NCLS + f];
        out[g * NCLS + f] = acc;
    }
}

extern "C" void kernel_launch(void* const* d_in, const int* in_sizes, int n_in,
                              void* d_out, int out_size, void* d_ws, size_t ws_size,
                              hipStream_t stream) {
    const float* x     = (const float*)d_in[0];
    const int*   eidx  = (const int*)d_in[1];
    const int*   batch = (const int*)d_in[2];
    const float* W1l   = (const float*)d_in[3];
    const float* b1    = (const float*)d_in[4];
    const float* W1r   = (const float*)d_in[5];
    const float* W2l   = (const float*)d_in[6];
    const float* b2    = (const float*)d_in[7];
    const float* W2r   = (const float*)d_in[8];
    const float* Wc    = (const float*)d_in[9];
    const float* bc    = (const float*)d_in[10];
    float* out = (float*)d_out;

    const int* src = eidx;
    const int* dst = eidx + N_EDGES;

    // workspace layout — total ~38.0 MB (R1's proven-safe usage was 40.3 MB)
    char* p = (char*)d_ws;
    unsigned int* bins = (unsigned int*)p;  p += (size_t)N_EDGES * 4;       // 12.8 MB
    float* h1   = (float*)p;                p += (size_t)N_NODES * 64 * 4;  // 25.6 MB
    int*   S    = (int*)p;                  p += (size_t)SCAN_N * 4;        // 0.80 MB
    int*   bsum = (int*)p;                  p += 256 * 4;
    int*   cnt  = (int*)p;                  p += (size_t)N_NODES * 4;       // 0.40 MB
    // ---- zeroed region ----
    float* gcnt   = (float*)p;              p += N_GRAPHS * 4;
    float* pooled = (float*)p;              p += (size_t)N_GRAPHS * 64 * 4;
    size_t zero_bytes = (size_t)(N_GRAPHS + N_GRAPHS * 64) * 4;

    hipMemsetAsync(gcnt, 0, zero_bytes, stream);

    k_hist <<<NB, 256, 0, stream>>>(dst, S);
    k_scan1<<<SCAN_NB1, 256, 0, stream>>>(S, bsum, SCAN_N);
    k_scan2<<<1, 64, 0, stream>>>(bsum, SCAN_NB1);
    k_scan3<<<(SCAN_N + 255) / 256, 256, 0, stream>>>(S, bsum, SCAN_N);
    k_bin  <<<NB, 256, 0, stream>>>(src, dst, S, bins);

    k_l1agg<<<K_BUCKETS, 256, 0, stream>>>(S, bins, x, W1l, b1, W1r, batch, gcnt, h1, cnt);
    k_node2<<<K_BUCKETS, 256, 0, stream>>>(S, bins, h1, cnt, W2l, b2, W2r, batch, gcnt, pooled);
    k_cls  <<<N_GRAPHS, 64, 0, stream>>>(pooled, Wc, bc, out);
}